// Round 4
// baseline (49.729 us; speedup 1.0000x reference)
//
#include <hip/hip_runtime.h>

#define NUM_INPUT   256
#define NUM_OUTPUT  64
#define MAX_DEPTH   10
#define N_INTERNAL  1023
#define STAGED_NODES 63          // tree levels 0..5 staged in LDS
#define STAGED_DEPTH 6
#define ELEMS_PER_WAVE 4         // 16 lanes per element
#define WAVES_PER_BLOCK 16
#define THREADS (WAVES_PER_BLOCK * 64)          // 1024
#define ELEMS_PER_BLOCK (WAVES_PER_BLOCK * ELEMS_PER_WAVE)  // 64

// Sum-reduce across each 16-lane row using DPP row_ror (VALU pipe, no DS ops).
__device__ __forceinline__ float group16_reduce(float acc) {
    int t;
    t = __builtin_amdgcn_update_dpp(0, __float_as_int(acc), 0x121, 0xf, 0xf, true); // row_ror:1
    acc += __int_as_float(t);
    t = __builtin_amdgcn_update_dpp(0, __float_as_int(acc), 0x122, 0xf, 0xf, true); // row_ror:2
    acc += __int_as_float(t);
    t = __builtin_amdgcn_update_dpp(0, __float_as_int(acc), 0x124, 0xf, 0xf, true); // row_ror:4
    acc += __int_as_float(t);
    t = __builtin_amdgcn_update_dpp(0, __float_as_int(acc), 0x128, 0xf, 0xf, true); // row_ror:8
    acc += __int_as_float(t);
    return acc;
}

__global__ __launch_bounds__(THREADS) void ogtree_kernel(
    const float* __restrict__ x,
    const float* __restrict__ W,
    const float* __restrict__ b,
    const float* __restrict__ alpha,
    const float* __restrict__ leaves,
    float* __restrict__ out)
{
    __shared__ float lds_w[STAGED_NODES * NUM_INPUT];  // 63 KB
    __shared__ float lds_b[N_INTERNAL];                // 4 KB
    __shared__ float lds_a[N_INTERNAL];                // 4 KB

    const int tid = threadIdx.x;

    // ---- stage W levels 0..5 (contiguous rows 0..62) + all b/alpha ----
    {
        const float4* Wv = reinterpret_cast<const float4*>(W);
        float4* lw4 = reinterpret_cast<float4*>(lds_w);
        #pragma unroll
        for (int i = tid; i < STAGED_NODES * NUM_INPUT / 4; i += THREADS)
            lw4[i] = Wv[i];
        for (int i = tid; i < N_INTERNAL; i += THREADS) {
            lds_b[i] = b[i];
            lds_a[i] = alpha[i];
        }
    }
    __syncthreads();

    const int lane = tid & 63;
    const int wid  = tid >> 6;
    const int g    = lane >> 4;   // element slot within wave (0..3)
    const int s    = lane & 15;   // sub-lane within element group
    const int elem = blockIdx.x * ELEMS_PER_BLOCK + wid * ELEMS_PER_WAVE + g;

    // ---- x fragment: 16 floats per lane, coalesced 256B per 16-lane group ----
    const float4* xrow = reinterpret_cast<const float4*>(x + (size_t)elem * NUM_INPUT);
    float4 xv0 = xrow[0 * 16 + s];
    float4 xv1 = xrow[1 * 16 + s];
    float4 xv2 = xrow[2 * 16 + s];
    float4 xv3 = xrow[3 * 16 + s];

    int   idx  = 0;
    float mult = 1.0f;

    // ---- depths 0..5: W from LDS; batch all 4 row-fragment loads up front ----
    #pragma unroll
    for (int d = 0; d < STAGED_DEPTH; ++d) {
        const float4* wrow = reinterpret_cast<const float4*>(lds_w + idx * NUM_INPUT);
        // all four ds_read_b128 issued before any FMA consumes them
        float4 w0 = wrow[0 * 16 + s];
        float4 w1 = wrow[1 * 16 + s];
        float4 w2 = wrow[2 * 16 + s];
        float4 w3 = wrow[3 * 16 + s];
        float acc = 0.0f;
        acc = fmaf(xv0.x, w0.x, acc); acc = fmaf(xv0.y, w0.y, acc);
        acc = fmaf(xv0.z, w0.z, acc); acc = fmaf(xv0.w, w0.w, acc);
        acc = fmaf(xv1.x, w1.x, acc); acc = fmaf(xv1.y, w1.y, acc);
        acc = fmaf(xv1.z, w1.z, acc); acc = fmaf(xv1.w, w1.w, acc);
        acc = fmaf(xv2.x, w2.x, acc); acc = fmaf(xv2.y, w2.y, acc);
        acc = fmaf(xv2.z, w2.z, acc); acc = fmaf(xv2.w, w2.w, acc);
        acc = fmaf(xv3.x, w3.x, acc); acc = fmaf(xv3.y, w3.y, acc);
        acc = fmaf(xv3.z, w3.z, acc); acc = fmaf(xv3.w, w3.w, acc);
        acc = group16_reduce(acc);
        float z   = lds_a[idx] * (acc + lds_b[idx]);
        float val = 1.0f / (1.0f + __expf(-z));
        bool  right = (val >= 0.5f);
        mult *= right ? val : (1.0f - val);
        idx = 2 * idx + 1 + (right ? 1 : 0);
    }

    // ---- depths 6..9: W from global (L2-resident); batch the 4 loads ----
    #pragma unroll
    for (int d = STAGED_DEPTH; d < MAX_DEPTH; ++d) {
        const float4* wrow = reinterpret_cast<const float4*>(W + (size_t)idx * NUM_INPUT);
        float4 w0 = wrow[0 * 16 + s];
        float4 w1 = wrow[1 * 16 + s];
        float4 w2 = wrow[2 * 16 + s];
        float4 w3 = wrow[3 * 16 + s];
        float acc = 0.0f;
        acc = fmaf(xv0.x, w0.x, acc); acc = fmaf(xv0.y, w0.y, acc);
        acc = fmaf(xv0.z, w0.z, acc); acc = fmaf(xv0.w, w0.w, acc);
        acc = fmaf(xv1.x, w1.x, acc); acc = fmaf(xv1.y, w1.y, acc);
        acc = fmaf(xv1.z, w1.z, acc); acc = fmaf(xv1.w, w1.w, acc);
        acc = fmaf(xv2.x, w2.x, acc); acc = fmaf(xv2.y, w2.y, acc);
        acc = fmaf(xv2.z, w2.z, acc); acc = fmaf(xv2.w, w2.w, acc);
        acc = fmaf(xv3.x, w3.x, acc); acc = fmaf(xv3.y, w3.y, acc);
        acc = fmaf(xv3.z, w3.z, acc); acc = fmaf(xv3.w, w3.w, acc);
        acc = group16_reduce(acc);
        float z   = lds_a[idx] * (acc + lds_b[idx]);
        float val = 1.0f / (1.0f + __expf(-z));
        bool  right = (val >= 0.5f);
        mult *= right ? val : (1.0f - val);
        idx = 2 * idx + 1 + (right ? 1 : 0);
    }

    // ---- epilogue: out[elem] = mult * leaves[idx - 1023] ----
    const int leaf = idx - N_INTERNAL;
    const float4 lv = reinterpret_cast<const float4*>(
        leaves + (size_t)leaf * NUM_OUTPUT)[s];
    float4 o;
    o.x = mult * lv.x;
    o.y = mult * lv.y;
    o.z = mult * lv.z;
    o.w = mult * lv.w;
    reinterpret_cast<float4*>(out + (size_t)elem * NUM_OUTPUT)[s] = o;
}

extern "C" void kernel_launch(void* const* d_in, const int* in_sizes, int n_in,
                              void* d_out, int out_size, void* d_ws, size_t ws_size,
                              hipStream_t stream) {
    const float* x      = (const float*)d_in[0];
    const float* W      = (const float*)d_in[1];
    const float* b      = (const float*)d_in[2];
    const float* alpha  = (const float*)d_in[3];
    const float* leaves = (const float*)d_in[4];
    float* out = (float*)d_out;

    const int batch  = in_sizes[0] / NUM_INPUT;           // 131072
    const int blocks = batch / ELEMS_PER_BLOCK;           // 2048

    ogtree_kernel<<<blocks, THREADS, 0, stream>>>(x, W, b, alpha, leaves, out);
}